// Round 5
// baseline (174.091 us; speedup 1.0000x reference)
//
#include <hip/hip_runtime.h>

// MultiHeadAttention: B=8, S=2048, D=256, H=4, hd=64
// R5: attn = 32 q per wave (2-wave blocks): K/V frag reads amortized over 2
//     q-groups -> LDS read traffic per block-iter 73.7KB -> 41KB (LDS pipe was
//     the saturated resource at ~56-73%). qkv_gemm: 256x64 tile (2x MFMA per
//     LDS read). Keeps R4's raw s_barrier + dbuf staging + fixed-exponent
//     exact softmax (P=exp2(st), scale-invariant, st bounded -> no overflow).
// MFMA layouts (m89/m91 HW-verified):
//   A-frag: lane holds A[m=lane&15][k=(lane>>4)*8+j]
//   B-frag: lane holds B[k=(lane>>4)*8+j][n=lane&15]
//   C/D:    lane,reg holds D[row=(lane>>4)*4+reg][col=lane&15]

typedef unsigned short u16;
typedef __bf16 bf16x8 __attribute__((ext_vector_type(8)));
typedef float  f32x4  __attribute__((ext_vector_type(4)));
typedef unsigned int u32x4 __attribute__((ext_vector_type(4)));
typedef unsigned int u32x2 __attribute__((ext_vector_type(2)));

#define LOG2E   1.4426950408889634f
#define ATTN_SC (0.125f * LOG2E)    // 1/sqrt(64) * log2(e), folded into Q
#define PSTR    2097152             // 16384*128: one K-panel of X / ctx (elements)
#define WPSTR   32768               // 256*128: one K-panel of W^T
#define WZSTR   65536               // per weight matrix (2 panels)

__device__ __forceinline__ u16 f2b(float f) {            // fp32 -> bf16 RNE
  unsigned u = __builtin_bit_cast(unsigned, f);
  u += 0x7FFFu + ((u >> 16) & 1u);
  return (u16)(u >> 16);
}
__device__ __forceinline__ float b2f(u16 b) {
  return __builtin_bit_cast(float, (unsigned)b << 16);
}
__device__ __forceinline__ unsigned pack_trunc(float a, float b) {
  return (__builtin_bit_cast(unsigned, a) >> 16) | (__builtin_bit_cast(unsigned, b) & 0xFFFF0000u);
}
__device__ __forceinline__ unsigned pack_rne(float a, float b) {
  return (unsigned)f2b(a) | ((unsigned)f2b(b) << 16);
}
__device__ __forceinline__ f32x4 mfma16(bf16x8 a, bf16x8 b, f32x4 c) {
  return __builtin_amdgcn_mfma_f32_16x16x32_bf16(a, b, c, 0, 0, 0);
}
// async global->LDS, 16B/lane; LDS dest = wave-uniform base + lane*16
__device__ __forceinline__ void cp16(const u16* g, u16* l) {
  __builtin_amdgcn_global_load_lds((const __attribute__((address_space(1))) void*)g,
                                   (__attribute__((address_space(3))) void*)l, 16, 0, 0);
}

// ---------------- fused prep: x convert + W transpose panel-major ----------------
template <typename T>
__global__ __launch_bounds__(256) void prep(const T* __restrict__ x,
                                            const T* __restrict__ W0, const T* __restrict__ W1,
                                            const T* __restrict__ W2, const T* __restrict__ W3,
                                            const T* __restrict__ b0, const T* __restrict__ b1,
                                            const T* __restrict__ b2, const T* __restrict__ b3,
                                            u16* __restrict__ xp, u16* __restrict__ WTp,
                                            float* __restrict__ biasf) {
  int bid = blockIdx.x;
  if (bid < 4096) {                                      // ---- x: [16384][256] -> panel-major
    int i0 = (bid * 256 + threadIdx.x) * 4;
    int row = i0 >> 8, col = i0 & 255;
    int p = col >> 7, pc = col & 127;
    u16* o = xp + (size_t)p * PSTR + (size_t)row * 128 + pc;
#pragma unroll
    for (int j = 0; j < 4; ++j) {
      if constexpr (sizeof(T) == 4) o[j] = f2b((float)x[i0 + j]);
      else                          o[j] = (u16)x[i0 + j];
    }
  } else {                                               // ---- weights + biases
    bid -= 4096;
    const int z = bid >> 8;
    const T* W = z == 0 ? W0 : z == 1 ? W1 : z == 2 ? W2 : W3;
    const T* b = z == 0 ? b0 : z == 1 ? b1 : z == 2 ? b2 : b3;
    int idx = (bid & 255) * 256 + threadIdx.x;
    int k = idx >> 8, n = idx & 255;
    u16 wb;
    if constexpr (sizeof(T) == 4) wb = f2b((float)W[k * 256 + n]);
    else                          wb = (u16)W[k * 256 + n];
    WTp[z * WZSTR + (k >> 7) * WPSTR + n * 128 + (k & 127)] = wb;
    if (idx < 256) {
      float bv;
      if constexpr (sizeof(T) == 4) bv = (float)b[idx];
      else                          bv = b2f((u16)b[idx]);
      biasf[z * 256 + idx] = bv;
    }
  }
}

// ---------------- QKV projection: 256x64 tile, K=256 (2 panels of 128) ----------------
// grid (64, 4, 3), 256 thr. Wave w owns m-rows [w*64, +64) of the 256-row tile
// (4 m-blocks). Per kc: 4 A + 4 B frag reads serve 16 MFMAs.
__global__ __launch_bounds__(256, 2) void qkv_gemm(const u16* __restrict__ xp, const u16* __restrict__ WTp,
                                                   const float* __restrict__ biasf,
                                                   u16* __restrict__ Qw, u16* __restrict__ Kw,
                                                   u16* __restrict__ VTg) {
  __shared__ __align__(16) u16 Al[256 * 128];   // 64 KB
  __shared__ __align__(16) u16 Bl[64 * 128];    // 16 KB
  const int tid = threadIdx.x, w = tid >> 6, lane = tid & 63;
  const int l16 = lane & 15, quad = lane >> 4;
  const int z = blockIdx.z, n0 = blockIdx.y * 64, m0 = blockIdx.x * 256;
  const u16* Ab = xp + (size_t)m0 * 128;
  const u16* Bb = WTp + z * WZSTR + (size_t)n0 * 128;
  f32x4 acc[4][4];
#pragma unroll
  for (int mm = 0; mm < 4; ++mm)
#pragma unroll
    for (int nb = 0; nb < 4; ++nb) acc[mm][nb] = (f32x4){0.f, 0.f, 0.f, 0.f};

#pragma unroll
  for (int p = 0; p < 2; ++p) {
    __syncthreads();
    const u16* Ap = Ab + (size_t)p * PSTR;
    const u16* Bp = Bb + p * WPSTR;
#pragma unroll
    for (int i = 0; i < 16; ++i) {                // A: 256 rows x 16 chunks = 4096
      int slot = i * 256 + w * 64 + lane;
      int row = slot >> 4, pc = slot & 15, c = pc ^ (row & 15);
      cp16(Ap + (size_t)row * 128 + c * 8, Al + (i * 256 + w * 64) * 8);
    }
#pragma unroll
    for (int i = 0; i < 4; ++i) {                 // B: 64 rows x 16 chunks = 1024
      int slot = i * 256 + w * 64 + lane;
      int row = slot >> 4, pc = slot & 15, c = pc ^ (row & 15);
      cp16(Bp + (size_t)row * 128 + c * 8, Bl + (i * 256 + w * 64) * 8);
    }
    __syncthreads();
#pragma unroll
    for (int kc = 0; kc < 4; ++kc) {
      int ch = ((kc * 4 + quad) ^ l16) * 8;
      bf16x8 a[4], b[4];
#pragma unroll
      for (int mm = 0; mm < 4; ++mm)
        a[mm] = *(const bf16x8*)&Al[(w * 64 + mm * 16 + l16) * 128 + ch];
#pragma unroll
      for (int nb = 0; nb < 4; ++nb)
        b[nb] = *(const bf16x8*)&Bl[(nb * 16 + l16) * 128 + ch];
#pragma unroll
      for (int mm = 0; mm < 4; ++mm)
#pragma unroll
        for (int nb = 0; nb < 4; ++nb)
          acc[mm][nb] = mfma16(a[mm], b[nb], acc[mm][nb]);
    }
  }

  const float* bp = biasf + z * 256;
  const int bb = m0 >> 11, s0 = m0 & 2047, h = blockIdx.y;
  if (z < 2) {
    u16* dst = (z == 0) ? Qw : Kw;
    const float sc = (z == 0) ? ATTN_SC : 1.0f;
#pragma unroll
    for (int mm = 0; mm < 4; ++mm)
#pragma unroll
      for (int nb = 0; nb < 4; ++nb) {
        int d = nb * 16 + l16;
        float bv = bp[n0 + d];
#pragma unroll
        for (int r = 0; r < 4; ++r) {
          int s = s0 + w * 64 + mm * 16 + quad * 4 + r;
          dst[(((size_t)(bb * 4 + h) * 2048) + s) * 64 + d] = f2b((acc[mm][nb][r] + bv) * sc);
        }
      }
  } else {
    // V: transpose 256(s) x 64(d) tile through Al (reuse; [d 64][s 256], 32 chunks/row,
    // swizzle ^(d&31)), store V^T [B,H,hd,S] coalesced
    __syncthreads();
#pragma unroll
    for (int mm = 0; mm < 4; ++mm)
#pragma unroll
      for (int nb = 0; nb < 4; ++nb) {
        int d = nb * 16 + l16;
        float bv = bp[n0 + d];
        f32x4 v = acc[mm][nb];
        u32x2 dd = { pack_rne(v[0] + bv, v[1] + bv), pack_rne(v[2] + bv, v[3] + bv) };
        int cch = w * 8 + mm * 2 + (quad >> 1);            // logical 16B chunk along s
        *(u32x2*)&Al[d * 256 + ((cch ^ (d & 31))) * 8 + (quad & 1) * 4] = dd;
      }
    __syncthreads();
#pragma unroll
    for (int i = 0; i < 8; ++i) {
      int slot = i * 256 + tid;                            // 64 d-rows x 32 chunks
      int d = slot >> 5, pc = slot & 31;
      u32x4 vv = *(const u32x4*)&Al[d * 256 + ((pc ^ (d & 31))) * 8];
      *(u32x4*)(VTg + (((size_t)(bb * 4 + h) * 64) + d) * 2048 + s0 + pc * 8) = vv;
    }
  }
}

// ---------------- output projection: 128x64 tile (as R4) ----------------
template <bool OUT_BF16>
__global__ __launch_bounds__(256) void out_gemm(const u16* __restrict__ ctxp, const u16* __restrict__ WTp,
                                                const float* __restrict__ bo, void* __restrict__ outv) {
  __shared__ __align__(16) u16 Al[128 * 128];
  __shared__ __align__(16) u16 Bl[64 * 128];
  const int tid = threadIdx.x, w = tid >> 6, lane = tid & 63;
  const int l16 = lane & 15, quad = lane >> 4;
  const int n0 = blockIdx.y * 64, m0 = blockIdx.x * 128;
  const u16* Ab = ctxp + (size_t)m0 * 128;
  const u16* Bb = WTp + 3 * WZSTR + (size_t)n0 * 128;
  f32x4 acc[2][4];
#pragma unroll
  for (int mm = 0; mm < 2; ++mm)
#pragma unroll
    for (int nb = 0; nb < 4; ++nb) acc[mm][nb] = (f32x4){0.f, 0.f, 0.f, 0.f};

#pragma unroll
  for (int p = 0; p < 2; ++p) {
    __syncthreads();
    const u16* Ap = Ab + (size_t)p * PSTR;
    const u16* Bp = Bb + p * WPSTR;
#pragma unroll
    for (int i = 0; i < 8; ++i) {
      int slot = i * 256 + w * 64 + lane;
      int row = slot >> 4, pc = slot & 15, c = pc ^ (row & 15);
      cp16(Ap + (size_t)row * 128 + c * 8, Al + (i * 256 + w * 64) * 8);
    }
#pragma unroll
    for (int i = 0; i < 4; ++i) {
      int slot = i * 256 + w * 64 + lane;
      int row = slot >> 4, pc = slot & 15, c = pc ^ (row & 15);
      cp16(Bp + (size_t)row * 128 + c * 8, Bl + (i * 256 + w * 64) * 8);
    }
    __syncthreads();
#pragma unroll
    for (int kc = 0; kc < 4; ++kc) {
      int ch = ((kc * 4 + quad) ^ l16) * 8;
      bf16x8 a0 = *(const bf16x8*)&Al[(w * 32 + l16) * 128 + ch];
      bf16x8 a1 = *(const bf16x8*)&Al[(w * 32 + 16 + l16) * 128 + ch];
#pragma unroll
      for (int nb = 0; nb < 4; ++nb) {
        bf16x8 b = *(const bf16x8*)&Bl[(nb * 16 + l16) * 128 + ch];
        acc[0][nb] = mfma16(a0, b, acc[0][nb]);
        acc[1][nb] = mfma16(a1, b, acc[1][nb]);
      }
    }
  }
#pragma unroll
  for (int mm = 0; mm < 2; ++mm)
#pragma unroll
    for (int nb = 0; nb < 4; ++nb) {
      int n = n0 + nb * 16 + l16;
      float bv = bo[n];
#pragma unroll
      for (int r = 0; r < 4; ++r) {
        size_t m = m0 + w * 32 + mm * 16 + quad * 4 + r;
        float v = acc[mm][nb][r] + bv;
        if constexpr (OUT_BF16) ((u16*)outv)[m * 256 + n] = f2b(v);
        else                    ((float*)outv)[m * 256 + n] = v;
      }
    }
}

// ---------------- fused flash attention: 32 q per wave ----------------
// grid (32, 32), block 128 (2 waves). Wave w owns q in [q0+32w, +32) as two
// 16-q groups. K/V frag reads shared across both groups (2x LDS amortization).
// P = exp2(st) unnormalized (exact); raw s_barrier + dbuf staging.
__global__ __launch_bounds__(128, 2) void attn(const u16* __restrict__ Q, const u16* __restrict__ K,
                                               const u16* __restrict__ VT, u16* __restrict__ ctxp) {
  __shared__ __align__(16) u16 Kt[2][64 * 64];     // [key][d], swizzled ^(row&7)
  __shared__ __align__(16) u16 VTt[2][64 * 64];    // [d][key]
  __shared__ __align__(16) u16 Pt[2][2][16 * 64];  // [wave][qgroup][q][key]
  const int tid = threadIdx.x;
  const int w = tid >> 6, lane = tid & 63;
  const int l16 = lane & 15, quad = lane >> 4;
  const int bh = blockIdx.y, q0 = blockIdx.x * 64;
  const u16* Qp = Q + (size_t)bh * 2048 * 64;
  const u16* Kp = K + (size_t)bh * 2048 * 64;
  const u16* Vp = VT + (size_t)bh * 64 * 2048;     // [d][s]

  bf16x8 qf[2][2];                                 // [qgroup][kc]
#pragma unroll
  for (int g = 0; g < 2; ++g) {
    int qrow = q0 + w * 32 + g * 16 + l16;
    qf[g][0] = *(const bf16x8*)(Qp + (size_t)qrow * 64 + quad * 8);
    qf[g][1] = *(const bf16x8*)(Qp + (size_t)qrow * 64 + 32 + quad * 8);
  }

  f32x4 acc[2][4];                                 // [qgroup][d-block]
#pragma unroll
  for (int g = 0; g < 2; ++g)
#pragma unroll
    for (int nb = 0; nb < 4; ++nb) acc[g][nb] = (f32x4){0.f, 0.f, 0.f, 0.f};
  float dn[2] = {0.f, 0.f};

  // staging: 512 chunks/tensor over 128 threads -> 4 each; swizzle ^(row&7)
  int srow[4], scol[4];
#pragma unroll
  for (int i = 0; i < 4; ++i) {
    int slot = i * 128 + tid;
    srow[i] = slot >> 3;
    scol[i] = (slot & 7) ^ (srow[i] & 7);
  }

#define STAGE(kt_, buf_)                                                                   \
  do {                                                                                     \
    _Pragma("unroll")                                                                      \
    for (int i = 0; i < 4; ++i) {                                                          \
      cp16(Kp + (size_t)((kt_) * 64 + srow[i]) * 64 + scol[i] * 8,                         \
           &Kt[buf_][(i * 128 + w * 64) * 8]);                                             \
      cp16(Vp + (size_t)srow[i] * 2048 + (kt_) * 64 + scol[i] * 8,                         \
           &VTt[buf_][(i * 128 + w * 64) * 8]);                                            \
    }                                                                                      \
  } while (0)

  STAGE(0, 0);

  for (int kt = 0; kt < 32; ++kt) {
    const int buf = kt & 1;
    __builtin_amdgcn_s_waitcnt(0x0F70 /* vmcnt(0) */);    // my prefetch landed
    __asm__ __volatile__("" ::: "memory");
    __builtin_amdgcn_s_barrier();                          // raw: no compiler drain
    __asm__ __volatile__("" ::: "memory");
    if (kt < 31) STAGE(kt + 1, buf ^ 1);

    const u16* KtB = Kt[buf];
    const u16* VtB = VTt[buf];

    // hoist V-frags (shared across both q-groups)
    bf16x8 vbr[2][4];
#pragma unroll
    for (int m = 0; m < 2; ++m)
#pragma unroll
      for (int nbD = 0; nbD < 4; ++nbD)
        vbr[m][nbD] = *(const bf16x8*)&VtB[(nbD * 16 + l16) * 64 + (((m * 4 + quad) ^ (l16 & 7))) * 8];

    // S^T = K * Q^T : st[g][nbK] reg r -> key = nbK*16+quad*4+r, q = g*16+l16
    f32x4 st[2][4];
#pragma unroll
    for (int g = 0; g < 2; ++g)
#pragma unroll
      for (int nb = 0; nb < 4; ++nb) st[g][nb] = (f32x4){0.f, 0.f, 0.f, 0.f};
#pragma unroll
    for (int kc = 0; kc < 2; ++kc) {
#pragma unroll
      for (int nbK = 0; nbK < 4; ++nbK) {
        bf16x8 a = *(const bf16x8*)&KtB[(nbK * 16 + l16) * 64 + (((kc * 4 + quad) ^ (l16 & 7))) * 8];
        st[0][nbK] = mfma16(a, qf[0][kc], st[0][nbK]);     // A-frag reused for both groups
        st[1][nbK] = mfma16(a, qf[1][kc], st[1][nbK]);
      }
    }

    // P = exp2(st) (no max: exact by scale-invariance, st bounded); denom in VALU
#pragma unroll
    for (int g = 0; g < 2; ++g) {
      u16* Ptg = Pt[w][g];
#pragma unroll
      for (int nbK = 0; nbK < 4; ++nbK) {
        float p0 = exp2f(st[g][nbK][0]), p1 = exp2f(st[g][nbK][1]);
        float p2 = exp2f(st[g][nbK][2]), p3 = exp2f(st[g][nbK][3]);
        dn[g] += (p0 + p1) + (p2 + p3);
        u32x2 dd = { pack_trunc(p0, p1), pack_trunc(p2, p3) };
        int cch = nbK * 2 + (quad >> 1);
        *(u32x2*)&Ptg[l16 * 64 + ((cch ^ (l16 & 7))) * 8 + (quad & 1) * 4] = dd;
      }
    }

    // ctx^T += V^T * P^T (V-frags reused across groups)
#pragma unroll
    for (int m = 0; m < 2; ++m) {
#pragma unroll
      for (int g = 0; g < 2; ++g) {
        bf16x8 pb = *(const bf16x8*)&Pt[w][g][l16 * 64 + (((m * 4 + quad) ^ (l16 & 7))) * 8];
#pragma unroll
        for (int nbD = 0; nbD < 4; ++nbD)
          acc[g][nbD] = mfma16(vbr[m][nbD], pb, acc[g][nbD]);
      }
    }
  }
#undef STAGE

  // denom reduce across quads sharing q=l16
  float linv[2];
#pragma unroll
  for (int g = 0; g < 2; ++g) {
    float d = dn[g];
    d += __shfl_xor(d, 16);
    d += __shfl_xor(d, 32);
    linv[g] = 1.0f / d;
  }

  // epilogue: normalize, transpose via Pt[w] ([q 32][d 64]), b128 panel stores
#pragma unroll
  for (int g = 0; g < 2; ++g) {
    u16* Ptg = Pt[w][g];
#pragma unroll
    for (int nbD = 0; nbD < 4; ++nbD) {
      f32x4 v = acc[g][nbD];
      u32x2 dd = { pack_rne(v[0] * linv[g], v[1] * linv[g]),
                   pack_rne(v[2] * linv[g], v[3] * linv[g]) };
      int cch = nbD * 2 + (quad >> 1);
      *(u32x2*)&Ptg[l16 * 64 + ((cch ^ (l16 & 7))) * 8 + (quad & 1) * 4] = dd;
    }
  }
  const int bb = bh >> 2, h = bh & 3;
  const int p = h >> 1, pcol = (h & 1) * 64;
#pragma unroll
  for (int cc = 0; cc < 4; ++cc) {
    int slot = cc * 64 + lane;                     // 32 q-rows x 8 chunks
    int row = slot >> 3, pc = slot & 7;
    u32x4 vv = *(const u32x4*)&Pt[w][0][row * 64 + ((pc ^ (row & 7))) * 8];  // [g][16*64] contiguous
    size_t m = (size_t)bb * 2048 + q0 + w * 32 + row;
    *(u32x4*)&ctxp[(size_t)p * PSTR + m * 128 + pcol + pc * 8] = vv;
  }
}

// ---------------- host ----------------
extern "C" void kernel_launch(void* const* d_in, const int* in_sizes, int n_in,
                              void* d_out, int out_size, void* d_ws, size_t ws_size,
                              hipStream_t stream) {
  bool f32in = true;
  {
    void* basep = nullptr; size_t sz = 0;
    hipError_t e = hipMemGetAddressRange((hipDeviceptr_t*)&basep, &sz, (hipDeviceptr_t)d_in[0]);
    if (e == hipSuccess && sz > 0) f32in = sz >= (size_t)in_sizes[0] * 4;
    else f32in = false;
  }

  char* ws = (char*)d_ws;
  u16*   xp    = (u16*)(ws + 0);          // 8 MB: X panel-major [2][16384][128]; aliased by ctx after qkv
  u16*   ctxp  = xp;
  u16*   WTp   = (u16*)(ws + 8388608);    // 512 KB: W^T panel-major [4][2][256][128]
  float* biasf = (float*)(ws + 8912896);  // 4 KB
  u16*   Qw    = (u16*)(ws + 8916992);    // 8 MB [B,H,S,hd], pre-scaled by ATTN_SC
  u16*   Kw    = (u16*)(ws + 17305600);   // 8 MB [B,H,S,hd]
  u16*   VTg   = (u16*)(ws + 25694208);   // 8 MB [B,H,hd,S]

  if (f32in) {
    prep<float><<<5120, 256, 0, stream>>>(
        (const float*)d_in[0],
        (const float*)d_in[1], (const float*)d_in[3], (const float*)d_in[5], (const float*)d_in[7],
        (const float*)d_in[2], (const float*)d_in[4], (const float*)d_in[6], (const float*)d_in[8],
        xp, WTp, biasf);
  } else {
    prep<u16><<<5120, 256, 0, stream>>>(
        (const u16*)d_in[0],
        (const u16*)d_in[1], (const u16*)d_in[3], (const u16*)d_in[5], (const u16*)d_in[7],
        (const u16*)d_in[2], (const u16*)d_in[4], (const u16*)d_in[6], (const u16*)d_in[8],
        xp, WTp, biasf);
  }
  qkv_gemm<<<dim3(64, 4, 3), 256, 0, stream>>>(xp, WTp, biasf, Qw, Kw, VTg);
  attn<<<dim3(32, 32), 128, 0, stream>>>(Qw, Kw, VTg, ctxp);
  if (f32in) out_gemm<false><<<dim3(128, 4), 256, 0, stream>>>(ctxp, WTp, biasf + 3 * 256, d_out);
  else       out_gemm<true ><<<dim3(128, 4), 256, 0, stream>>>(ctxp, WTp, biasf + 3 * 256, d_out);
}

// Round 6
// 173.575 us; speedup vs baseline: 1.0030x; 1.0030x over previous
//
#include <hip/hip_runtime.h>

// MultiHeadAttention: B=8, S=2048, D=256, H=4, hd=64
// R6: attn K-split x2 (exact: fixed-exponent softmax makes partials linear):
//     grid (16 qtiles, 32 bh, 2 khalves), 4-wave blocks, 32 q/wave ->
//     4096 waves (3/SIMD with 48KB LDS) AND 2x LDS amortization.
//     Unnormalized bf16 partials -> half0 in xp region (dead), half1 in d_out
//     (ours to scribble; overwritten by out_gemm later); combine kernel merges,
//     normalizes, writes panel ctx into dead Qw region. Loop body = R5 verbatim.
// MFMA layouts (m89/m91 HW-verified):
//   A-frag: lane holds A[m=lane&15][k=(lane>>4)*8+j]
//   B-frag: lane holds B[k=(lane>>4)*8+j][n=lane&15]
//   C/D:    lane,reg holds D[row=(lane>>4)*4+reg][col=lane&15]

typedef unsigned short u16;
typedef __bf16 bf16x8 __attribute__((ext_vector_type(8)));
typedef float  f32x4  __attribute__((ext_vector_type(4)));
typedef unsigned int u32x4 __attribute__((ext_vector_type(4)));
typedef unsigned int u32x2 __attribute__((ext_vector_type(2)));

#define LOG2E   1.4426950408889634f
#define ATTN_SC (0.125f * LOG2E)    // 1/sqrt(64) * log2(e), folded into Q
#define PSTR    2097152             // 16384*128: one K-panel of X / ctx (elements)
#define WPSTR   32768               // 256*128: one K-panel of W^T
#define WZSTR   65536               // per weight matrix (2 panels)

__device__ __forceinline__ u16 f2b(float f) {            // fp32 -> bf16 RNE
  unsigned u = __builtin_bit_cast(unsigned, f);
  u += 0x7FFFu + ((u >> 16) & 1u);
  return (u16)(u >> 16);
}
__device__ __forceinline__ float b2f(u16 b) {
  return __builtin_bit_cast(float, (unsigned)b << 16);
}
__device__ __forceinline__ float b2f_hi(unsigned u) {    // high bf16 of a u32
  return __builtin_bit_cast(float, u & 0xFFFF0000u);
}
__device__ __forceinline__ float b2f_lo(unsigned u) {    // low bf16 of a u32
  return __builtin_bit_cast(float, u << 16);
}
__device__ __forceinline__ unsigned pack_trunc(float a, float b) {
  return (__builtin_bit_cast(unsigned, a) >> 16) | (__builtin_bit_cast(unsigned, b) & 0xFFFF0000u);
}
__device__ __forceinline__ unsigned pack_rne(float a, float b) {
  return (unsigned)f2b(a) | ((unsigned)f2b(b) << 16);
}
__device__ __forceinline__ f32x4 mfma16(bf16x8 a, bf16x8 b, f32x4 c) {
  return __builtin_amdgcn_mfma_f32_16x16x32_bf16(a, b, c, 0, 0, 0);
}
// async global->LDS, 16B/lane; LDS dest = wave-uniform base + lane*16
__device__ __forceinline__ void cp16(const u16* g, u16* l) {
  __builtin_amdgcn_global_load_lds((const __attribute__((address_space(1))) void*)g,
                                   (__attribute__((address_space(3))) void*)l, 16, 0, 0);
}

// ---------------- fused prep: x convert + W transpose panel-major ----------------
template <typename T>
__global__ __launch_bounds__(256) void prep(const T* __restrict__ x,
                                            const T* __restrict__ W0, const T* __restrict__ W1,
                                            const T* __restrict__ W2, const T* __restrict__ W3,
                                            const T* __restrict__ b0, const T* __restrict__ b1,
                                            const T* __restrict__ b2, const T* __restrict__ b3,
                                            u16* __restrict__ xp, u16* __restrict__ WTp,
                                            float* __restrict__ biasf) {
  int bid = blockIdx.x;
  if (bid < 4096) {                                      // ---- x: [16384][256] -> panel-major
    int i0 = (bid * 256 + threadIdx.x) * 4;
    int row = i0 >> 8, col = i0 & 255;
    int p = col >> 7, pc = col & 127;
    u16* o = xp + (size_t)p * PSTR + (size_t)row * 128 + pc;
#pragma unroll
    for (int j = 0; j < 4; ++j) {
      if constexpr (sizeof(T) == 4) o[j] = f2b((float)x[i0 + j]);
      else                          o[j] = (u16)x[i0 + j];
    }
  } else {                                               // ---- weights + biases
    bid -= 4096;
    const int z = bid >> 8;
    const T* W = z == 0 ? W0 : z == 1 ? W1 : z == 2 ? W2 : W3;
    const T* b = z == 0 ? b0 : z == 1 ? b1 : z == 2 ? b2 : b3;
    int idx = (bid & 255) * 256 + threadIdx.x;
    int k = idx >> 8, n = idx & 255;
    u16 wb;
    if constexpr (sizeof(T) == 4) wb = f2b((float)W[k * 256 + n]);
    else                          wb = (u16)W[k * 256 + n];
    WTp[z * WZSTR + (k >> 7) * WPSTR + n * 128 + (k & 127)] = wb;
    if (idx < 256) {
      float bv;
      if constexpr (sizeof(T) == 4) bv = (float)b[idx];
      else                          bv = b2f((u16)b[idx]);
      biasf[z * 256 + idx] = bv;
    }
  }
}

// ---------------- QKV projection: 256x64 tile, K=256 (2 panels of 128) ----------------
__global__ __launch_bounds__(256, 2) void qkv_gemm(const u16* __restrict__ xp, const u16* __restrict__ WTp,
                                                   const float* __restrict__ biasf,
                                                   u16* __restrict__ Qw, u16* __restrict__ Kw,
                                                   u16* __restrict__ VTg) {
  __shared__ __align__(16) u16 Al[256 * 128];   // 64 KB
  __shared__ __align__(16) u16 Bl[64 * 128];    // 16 KB
  const int tid = threadIdx.x, w = tid >> 6, lane = tid & 63;
  const int l16 = lane & 15, quad = lane >> 4;
  const int z = blockIdx.z, n0 = blockIdx.y * 64, m0 = blockIdx.x * 256;
  const u16* Ab = xp + (size_t)m0 * 128;
  const u16* Bb = WTp + z * WZSTR + (size_t)n0 * 128;
  f32x4 acc[4][4];
#pragma unroll
  for (int mm = 0; mm < 4; ++mm)
#pragma unroll
    for (int nb = 0; nb < 4; ++nb) acc[mm][nb] = (f32x4){0.f, 0.f, 0.f, 0.f};

#pragma unroll
  for (int p = 0; p < 2; ++p) {
    __syncthreads();
    const u16* Ap = Ab + (size_t)p * PSTR;
    const u16* Bp = Bb + p * WPSTR;
#pragma unroll
    for (int i = 0; i < 16; ++i) {                // A: 256 rows x 16 chunks = 4096
      int slot = i * 256 + w * 64 + lane;
      int row = slot >> 4, pc = slot & 15, c = pc ^ (row & 15);
      cp16(Ap + (size_t)row * 128 + c * 8, Al + (i * 256 + w * 64) * 8);
    }
#pragma unroll
    for (int i = 0; i < 4; ++i) {                 // B: 64 rows x 16 chunks = 1024
      int slot = i * 256 + w * 64 + lane;
      int row = slot >> 4, pc = slot & 15, c = pc ^ (row & 15);
      cp16(Bp + (size_t)row * 128 + c * 8, Bl + (i * 256 + w * 64) * 8);
    }
    __syncthreads();
#pragma unroll
    for (int kc = 0; kc < 4; ++kc) {
      int ch = ((kc * 4 + quad) ^ l16) * 8;
      bf16x8 a[4], b[4];
#pragma unroll
      for (int mm = 0; mm < 4; ++mm)
        a[mm] = *(const bf16x8*)&Al[(w * 64 + mm * 16 + l16) * 128 + ch];
#pragma unroll
      for (int nb = 0; nb < 4; ++nb)
        b[nb] = *(const bf16x8*)&Bl[(nb * 16 + l16) * 128 + ch];
#pragma unroll
      for (int mm = 0; mm < 4; ++mm)
#pragma unroll
        for (int nb = 0; nb < 4; ++nb)
          acc[mm][nb] = mfma16(a[mm], b[nb], acc[mm][nb]);
    }
  }

  const float* bp = biasf + z * 256;
  const int bb = m0 >> 11, s0 = m0 & 2047, h = blockIdx.y;
  if (z < 2) {
    u16* dst = (z == 0) ? Qw : Kw;
    const float sc = (z == 0) ? ATTN_SC : 1.0f;
#pragma unroll
    for (int mm = 0; mm < 4; ++mm)
#pragma unroll
      for (int nb = 0; nb < 4; ++nb) {
        int d = nb * 16 + l16;
        float bv = bp[n0 + d];
#pragma unroll
        for (int r = 0; r < 4; ++r) {
          int s = s0 + w * 64 + mm * 16 + quad * 4 + r;
          dst[(((size_t)(bb * 4 + h) * 2048) + s) * 64 + d] = f2b((acc[mm][nb][r] + bv) * sc);
        }
      }
  } else {
    // V: transpose 256(s) x 64(d) tile through Al, store V^T [B,H,hd,S] coalesced
    __syncthreads();
#pragma unroll
    for (int mm = 0; mm < 4; ++mm)
#pragma unroll
      for (int nb = 0; nb < 4; ++nb) {
        int d = nb * 16 + l16;
        float bv = bp[n0 + d];
        f32x4 v = acc[mm][nb];
        u32x2 dd = { pack_rne(v[0] + bv, v[1] + bv), pack_rne(v[2] + bv, v[3] + bv) };
        int cch = w * 8 + mm * 2 + (quad >> 1);            // logical 16B chunk along s
        *(u32x2*)&Al[d * 256 + ((cch ^ (d & 31))) * 8 + (quad & 1) * 4] = dd;
      }
    __syncthreads();
#pragma unroll
    for (int i = 0; i < 8; ++i) {
      int slot = i * 256 + tid;                            // 64 d-rows x 32 chunks
      int d = slot >> 5, pc = slot & 31;
      u32x4 vv = *(const u32x4*)&Al[d * 256 + ((pc ^ (d & 31))) * 8];
      *(u32x4*)(VTg + (((size_t)(bb * 4 + h) * 64) + d) * 2048 + s0 + pc * 8) = vv;
    }
  }
}

// ---------------- output projection: 128x64 tile ----------------
template <bool OUT_BF16>
__global__ __launch_bounds__(256) void out_gemm(const u16* __restrict__ ctxp, const u16* __restrict__ WTp,
                                                const float* __restrict__ bo, void* __restrict__ outv) {
  __shared__ __align__(16) u16 Al[128 * 128];
  __shared__ __align__(16) u16 Bl[64 * 128];
  const int tid = threadIdx.x, w = tid >> 6, lane = tid & 63;
  const int l16 = lane & 15, quad = lane >> 4;
  const int n0 = blockIdx.y * 64, m0 = blockIdx.x * 128;
  const u16* Ab = ctxp + (size_t)m0 * 128;
  const u16* Bb = WTp + 3 * WZSTR + (size_t)n0 * 128;
  f32x4 acc[2][4];
#pragma unroll
  for (int mm = 0; mm < 2; ++mm)
#pragma unroll
    for (int nb = 0; nb < 4; ++nb) acc[mm][nb] = (f32x4){0.f, 0.f, 0.f, 0.f};

#pragma unroll
  for (int p = 0; p < 2; ++p) {
    __syncthreads();
    const u16* Ap = Ab + (size_t)p * PSTR;
    const u16* Bp = Bb + p * WPSTR;
#pragma unroll
    for (int i = 0; i < 8; ++i) {
      int slot = i * 256 + w * 64 + lane;
      int row = slot >> 4, pc = slot & 15, c = pc ^ (row & 15);
      cp16(Ap + (size_t)row * 128 + c * 8, Al + (i * 256 + w * 64) * 8);
    }
#pragma unroll
    for (int i = 0; i < 4; ++i) {
      int slot = i * 256 + w * 64 + lane;
      int row = slot >> 4, pc = slot & 15, c = pc ^ (row & 15);
      cp16(Bp + (size_t)row * 128 + c * 8, Bl + (i * 256 + w * 64) * 8);
    }
    __syncthreads();
#pragma unroll
    for (int kc = 0; kc < 4; ++kc) {
      int ch = ((kc * 4 + quad) ^ l16) * 8;
      bf16x8 a0 = *(const bf16x8*)&Al[(w * 32 + l16) * 128 + ch];
      bf16x8 a1 = *(const bf16x8*)&Al[(w * 32 + 16 + l16) * 128 + ch];
#pragma unroll
      for (int nb = 0; nb < 4; ++nb) {
        bf16x8 b = *(const bf16x8*)&Bl[(nb * 16 + l16) * 128 + ch];
        acc[0][nb] = mfma16(a0, b, acc[0][nb]);
        acc[1][nb] = mfma16(a1, b, acc[1][nb]);
      }
    }
  }
#pragma unroll
  for (int mm = 0; mm < 2; ++mm)
#pragma unroll
    for (int nb = 0; nb < 4; ++nb) {
      int n = n0 + nb * 16 + l16;
      float bv = bo[n];
#pragma unroll
      for (int r = 0; r < 4; ++r) {
        size_t m = m0 + w * 32 + mm * 16 + quad * 4 + r;
        float v = acc[mm][nb][r] + bv;
        if constexpr (OUT_BF16) ((u16*)outv)[m * 256 + n] = f2b(v);
        else                    ((float*)outv)[m * 256 + n] = v;
      }
    }
}

// ---------------- fused flash attention: 32 q/wave, K-split x2 ----------------
// grid (16 qtiles, 32 bh, 2 khalf), block 256 (4 waves). Wave w: q in
// [q0+32w, +32) as two 16-q groups; block processes keys [z*1024, +1024).
// P = exp2(st) unnormalized (exact by scale-invariance; partials linear).
// Outputs UNNORMALIZED bf16 partial ctx [bh][q][64] + per-q denom.
__global__ __launch_bounds__(256, 3) void attn(const u16* __restrict__ Q, const u16* __restrict__ K,
                                               const u16* __restrict__ VT,
                                               u16* __restrict__ P0, u16* __restrict__ P1,
                                               float* __restrict__ dnb) {
  __shared__ __align__(16) u16 Kt[2][64 * 64];     // [key][d], swizzled ^(row&7)
  __shared__ __align__(16) u16 VTt[2][64 * 64];    // [d][key]
  __shared__ __align__(16) u16 Pt[4][2][16 * 64];  // [wave][qgroup][q][key]
  const int tid = threadIdx.x;
  const int w = tid >> 6, lane = tid & 63;
  const int l16 = lane & 15, quad = lane >> 4;
  const int bh = blockIdx.y, q0 = blockIdx.x * 128, z = blockIdx.z;
  const u16* Qp = Q + (size_t)bh * 2048 * 64;
  const u16* Kp = K + (size_t)bh * 2048 * 64 + (size_t)z * 1024 * 64;
  const u16* Vp = VT + (size_t)bh * 64 * 2048 + z * 1024;   // [d][s], s-offset

  bf16x8 qf[2][2];                                 // [qgroup][kc]
#pragma unroll
  for (int g = 0; g < 2; ++g) {
    int qrow = q0 + w * 32 + g * 16 + l16;
    qf[g][0] = *(const bf16x8*)(Qp + (size_t)qrow * 64 + quad * 8);
    qf[g][1] = *(const bf16x8*)(Qp + (size_t)qrow * 64 + 32 + quad * 8);
  }

  f32x4 acc[2][4];                                 // [qgroup][d-block]
#pragma unroll
  for (int g = 0; g < 2; ++g)
#pragma unroll
    for (int nb = 0; nb < 4; ++nb) acc[g][nb] = (f32x4){0.f, 0.f, 0.f, 0.f};
  float dn[2] = {0.f, 0.f};

  // staging: 512 chunks/tensor over 256 threads -> 2 each; swizzle ^(row&7)
  const int sl0 = tid, sl1 = 256 + tid;
  const int r0 = sl0 >> 3, c0 = (sl0 & 7) ^ (r0 & 7);
  const int r1 = sl1 >> 3, c1 = (sl1 & 7) ^ (r1 & 7);

#define STAGE(kt_, buf_)                                                                   \
  do {                                                                                     \
    cp16(Kp + (size_t)((kt_) * 64 + r0) * 64 + c0 * 8, &Kt[buf_][(w * 64) * 8]);           \
    cp16(Kp + (size_t)((kt_) * 64 + r1) * 64 + c1 * 8, &Kt[buf_][(256 + w * 64) * 8]);     \
    cp16(Vp + (size_t)r0 * 2048 + (kt_) * 64 + c0 * 8, &VTt[buf_][(w * 64) * 8]);          \
    cp16(Vp + (size_t)r1 * 2048 + (kt_) * 64 + c1 * 8, &VTt[buf_][(256 + w * 64) * 8]);    \
  } while (0)

  STAGE(0, 0);

  for (int kt = 0; kt < 16; ++kt) {
    const int buf = kt & 1;
    __builtin_amdgcn_s_waitcnt(0x0F70 /* vmcnt(0) */);    // my prefetch landed
    __asm__ __volatile__("" ::: "memory");
    __builtin_amdgcn_s_barrier();                          // raw: no compiler drain
    __asm__ __volatile__("" ::: "memory");
    if (kt < 15) STAGE(kt + 1, buf ^ 1);

    const u16* KtB = Kt[buf];
    const u16* VtB = VTt[buf];

    // hoist V-frags (shared across both q-groups)
    bf16x8 vbr[2][4];
#pragma unroll
    for (int m = 0; m < 2; ++m)
#pragma unroll
      for (int nbD = 0; nbD < 4; ++nbD)
        vbr[m][nbD] = *(const bf16x8*)&VtB[(nbD * 16 + l16) * 64 + (((m * 4 + quad) ^ (l16 & 7))) * 8];

    // S^T = K * Q^T : st[g][nbK] reg r -> key = nbK*16+quad*4+r, q = g*16+l16
    f32x4 st[2][4];
#pragma unroll
    for (int g = 0; g < 2; ++g)
#pragma unroll
      for (int nb = 0; nb < 4; ++nb) st[g][nb] = (f32x4){0.f, 0.f, 0.f, 0.f};
#pragma unroll
    for (int kc = 0; kc < 2; ++kc) {
#pragma unroll
      for (int nbK = 0; nbK < 4; ++nbK) {
        bf16x8 a = *(const bf16x8*)&KtB[(nbK * 16 + l16) * 64 + (((kc * 4 + quad) ^ (l16 & 7))) * 8];
        st[0][nbK] = mfma16(a, qf[0][kc], st[0][nbK]);     // A-frag reused for both groups
        st[1][nbK] = mfma16(a, qf[1][kc], st[1][nbK]);
      }
    }

    // P = exp2(st) (no max: exact by scale-invariance, st bounded); denom in VALU
#pragma unroll
    for (int g = 0; g < 2; ++g) {
      u16* Ptg = Pt[w][g];
#pragma unroll
      for (int nbK = 0; nbK < 4; ++nbK) {
        float p0 = exp2f(st[g][nbK][0]), p1 = exp2f(st[g][nbK][1]);
        float p2 = exp2f(st[g][nbK][2]), p3 = exp2f(st[g][nbK][3]);
        dn[g] += (p0 + p1) + (p2 + p3);
        u32x2 dd = { pack_trunc(p0, p1), pack_trunc(p2, p3) };
        int cch = nbK * 2 + (quad >> 1);
        *(u32x2*)&Ptg[l16 * 64 + ((cch ^ (l16 & 7))) * 8 + (quad & 1) * 4] = dd;
      }
    }

    // ctx^T += V^T * P^T (V-frags reused across groups)
#pragma unroll
    for (int m = 0; m < 2; ++m) {
#pragma unroll
      for (int g = 0; g < 2; ++g) {
        bf16x8 pb = *(const bf16x8*)&Pt[w][g][l16 * 64 + (((m * 4 + quad) ^ (l16 & 7))) * 8];
#pragma unroll
        for (int nbD = 0; nbD < 4; ++nbD)
          acc[g][nbD] = mfma16(vbr[m][nbD], pb, acc[g][nbD]);
      }
    }
  }
#undef STAGE

  // denom reduce across quads sharing q=l16; store per-q denom
  u16* pdst = z ? P1 : P0;
#pragma unroll
  for (int g = 0; g < 2; ++g) {
    float d = dn[g];
    d += __shfl_xor(d, 16);
    d += __shfl_xor(d, 32);
    dn[g] = d;
    if (quad == 0)
      dnb[z * 65536 + bh * 2048 + q0 + w * 32 + g * 16 + l16] = d;
  }

  // epilogue: UNNORMALIZED partial ctx, transpose via Pt[w] ([q 32][d 64]), b128 stores
#pragma unroll
  for (int g = 0; g < 2; ++g) {
    u16* Ptg = Pt[w][g];
#pragma unroll
    for (int nbD = 0; nbD < 4; ++nbD) {
      f32x4 v = acc[g][nbD];
      u32x2 dd = { pack_rne(v[0], v[1]), pack_rne(v[2], v[3]) };
      int cch = nbD * 2 + (quad >> 1);
      *(u32x2*)&Ptg[l16 * 64 + ((cch ^ (l16 & 7))) * 8 + (quad & 1) * 4] = dd;
    }
  }
#pragma unroll
  for (int cc = 0; cc < 4; ++cc) {
    int slot = cc * 64 + lane;                     // 32 q-rows x 8 chunks
    int row = slot >> 3, pc = slot & 7;
    u32x4 vv = *(const u32x4*)&Pt[w][0][row * 64 + ((pc ^ (row & 7))) * 8];
    size_t qg = q0 + w * 32 + row;
    *(u32x4*)(pdst + (((size_t)bh * 2048) + qg) * 64 + pc * 8) = vv;
  }
}

// ---------------- combine: merge k-halves, normalize, panel-major ctx ----------------
__global__ __launch_bounds__(256) void combine(const u16* __restrict__ p0, const u16* __restrict__ p1,
                                               const float* __restrict__ dnb, u16* __restrict__ ctxp) {
  int t = blockIdx.x * 256 + threadIdx.x;          // 524288 = 32bh * 2048q * 8chunks
  int chunk = t & 7, q = (t >> 3) & 2047, bh = t >> 14;
  size_t idx = ((((size_t)bh * 2048) + q) * 64) + chunk * 8;
  u32x4 a = *(const u32x4*)(p0 + idx);
  u32x4 b = *(const u32x4*)(p1 + idx);
  float l = 1.0f / (dnb[bh * 2048 + q] + dnb[65536 + bh * 2048 + q]);
  u32x4 o;
#pragma unroll
  for (int i = 0; i < 4; ++i) {
    float lo = (b2f_lo(a[i]) + b2f_lo(b[i])) * l;
    float hi = (b2f_hi(a[i]) + b2f_hi(b[i])) * l;
    o[i] = pack_rne(lo, hi);
  }
  int bb = bh >> 2, h = bh & 3, p = h >> 1, pcol = (h & 1) * 64;
  size_t m = (size_t)bb * 2048 + q;
  *(u32x4*)(ctxp + (size_t)p * PSTR + m * 128 + pcol + chunk * 8) = o;
}

// ---------------- host ----------------
extern "C" void kernel_launch(void* const* d_in, const int* in_sizes, int n_in,
                              void* d_out, int out_size, void* d_ws, size_t ws_size,
                              hipStream_t stream) {
  bool f32in = true;
  {
    void* basep = nullptr; size_t sz = 0;
    hipError_t e = hipMemGetAddressRange((hipDeviceptr_t*)&basep, &sz, (hipDeviceptr_t)d_in[0]);
    if (e == hipSuccess && sz > 0) f32in = sz >= (size_t)in_sizes[0] * 4;
    else f32in = false;
  }

  char* ws = (char*)d_ws;
  u16*   xp    = (u16*)(ws + 0);          // 8 MB: X panel-major [2][16384][128]; reused as attn partial p0
  u16*   WTp   = (u16*)(ws + 8388608);    // 512 KB: W^T panel-major [4][2][256][128]
  float* biasf = (float*)(ws + 8912896);  // 4 KB
  u16*   Qw    = (u16*)(ws + 8916992);    // 8 MB [B,H,S,hd], pre-scaled; reused as panel ctx after attn
  u16*   Kw    = (u16*)(ws + 17305600);   // 8 MB [B,H,S,hd]
  u16*   VTg   = (u16*)(ws + 25694208);   // 8 MB [B,H,hd,S]
  float* dnb   = (float*)(ws + 34082816); // 512 KB: per-q denom, 2 k-halves
  u16*   part0 = xp;                      // attn partial half 0 (x dead after qkv)
  u16*   part1 = (u16*)d_out;             // attn partial half 1 (d_out ours; overwritten by out_gemm)
  u16*   ctxp  = Qw;                      // combined panel ctx (Q dead after attn)

  if (f32in) {
    prep<float><<<5120, 256, 0, stream>>>(
        (const float*)d_in[0],
        (const float*)d_in[1], (const float*)d_in[3], (const float*)d_in[5], (const float*)d_in[7],
        (const float*)d_in[2], (const float*)d_in[4], (const float*)d_in[6], (const float*)d_in[8],
        xp, WTp, biasf);
  } else {
    prep<u16><<<5120, 256, 0, stream>>>(
        (const u16*)d_in[0],
        (const u16*)d_in[1], (const u16*)d_in[3], (const u16*)d_in[5], (const u16*)d_in[7],
        (const u16*)d_in[2], (const u16*)d_in[4], (const u16*)d_in[6], (const u16*)d_in[8],
        xp, WTp, biasf);
  }
  qkv_gemm<<<dim3(64, 4, 3), 256, 0, stream>>>(xp, WTp, biasf, Qw, Kw, VTg);
  attn<<<dim3(16, 32, 2), 256, 0, stream>>>(Qw, Kw, VTg, part0, part1, dnb);
  combine<<<2048, 256, 0, stream>>>(part0, part1, dnb, ctxp);
  if (f32in) out_gemm<false><<<dim3(128, 4), 256, 0, stream>>>(ctxp, WTp, biasf + 3 * 256, d_out);
  else       out_gemm<true ><<<dim3(128, 4), 256, 0, stream>>>(ctxp, WTp, biasf + 3 * 256, d_out);
}

// Round 7
// 169.115 us; speedup vs baseline: 1.0294x; 1.0264x over previous
//
#include <hip/hip_runtime.h>

// MultiHeadAttention: B=8, S=2048, D=256, H=4, hd=64
// R7: attn LDS 48->40KB (per-wave P buffer shared between q-groups, serialized
//     g-phases; wave-in-order DS makes the reuse safe) -> exactly 4 blocks/CU,
//     1024-block grid = one full residency wave, zero tail. qkv reads x
//     directly (inline convert in A-staging); prep = weights only. combine
//     fused into out_gemm (ws-gated; fallback = R6 combine path). 4 launches.
// MFMA layouts (m89/m91 HW-verified):
//   A-frag: lane holds A[m=lane&15][k=(lane>>4)*8+j]
//   B-frag: lane holds B[k=(lane>>4)*8+j][n=lane&15]
//   C/D:    lane,reg holds D[row=(lane>>4)*4+reg][col=lane&15]

typedef unsigned short u16;
typedef __bf16 bf16x8 __attribute__((ext_vector_type(8)));
typedef float  f32x4  __attribute__((ext_vector_type(4)));
typedef unsigned int u32x4 __attribute__((ext_vector_type(4)));
typedef unsigned int u32x2 __attribute__((ext_vector_type(2)));

#define LOG2E   1.4426950408889634f
#define ATTN_SC (0.125f * LOG2E)    // 1/sqrt(64) * log2(e), folded into Q
#define WPSTR   32768               // 256*128: one K-panel of W^T
#define WZSTR   65536               // per weight matrix (2 panels)

__device__ __forceinline__ u16 f2b(float f) {            // fp32 -> bf16 RNE
  unsigned u = __builtin_bit_cast(unsigned, f);
  u += 0x7FFFu + ((u >> 16) & 1u);
  return (u16)(u >> 16);
}
__device__ __forceinline__ float b2f(u16 b) {
  return __builtin_bit_cast(float, (unsigned)b << 16);
}
__device__ __forceinline__ float b2f_hi(unsigned u) {
  return __builtin_bit_cast(float, u & 0xFFFF0000u);
}
__device__ __forceinline__ float b2f_lo(unsigned u) {
  return __builtin_bit_cast(float, u << 16);
}
__device__ __forceinline__ unsigned pack_trunc(float a, float b) {
  return (__builtin_bit_cast(unsigned, a) >> 16) | (__builtin_bit_cast(unsigned, b) & 0xFFFF0000u);
}
__device__ __forceinline__ unsigned pack_rne(float a, float b) {
  return (unsigned)f2b(a) | ((unsigned)f2b(b) << 16);
}
__device__ __forceinline__ f32x4 mfma16(bf16x8 a, bf16x8 b, f32x4 c) {
  return __builtin_amdgcn_mfma_f32_16x16x32_bf16(a, b, c, 0, 0, 0);
}
// async global->LDS, 16B/lane; LDS dest = wave-uniform base + lane*16
__device__ __forceinline__ void cp16(const u16* g, u16* l) {
  __builtin_amdgcn_global_load_lds((const __attribute__((address_space(1))) void*)g,
                                   (__attribute__((address_space(3))) void*)l, 16, 0, 0);
}

// ---------------- prep: weights + biases only ----------------
template <typename T>
__global__ __launch_bounds__(256) void prep(const T* __restrict__ W0, const T* __restrict__ W1,
                                            const T* __restrict__ W2, const T* __restrict__ W3,
                                            const T* __restrict__ b0, const T* __restrict__ b1,
                                            const T* __restrict__ b2, const T* __restrict__ b3,
                                            u16* __restrict__ WTp, float* __restrict__ biasf) {
  const int z = blockIdx.x >> 8;
  const T* W = z == 0 ? W0 : z == 1 ? W1 : z == 2 ? W2 : W3;
  const T* b = z == 0 ? b0 : z == 1 ? b1 : z == 2 ? b2 : b3;
  int idx = (blockIdx.x & 255) * 256 + threadIdx.x;   // 65536 per z
  int k = idx >> 8, n = idx & 255;
  u16 wb;
  if constexpr (sizeof(T) == 4) wb = f2b((float)W[k * 256 + n]);
  else                          wb = (u16)W[k * 256 + n];
  WTp[z * WZSTR + (k >> 7) * WPSTR + n * 128 + (k & 127)] = wb;   // W^T panel-major
  if (idx < 256) {
    float bv;
    if constexpr (sizeof(T) == 4) bv = (float)b[idx];
    else                          bv = b2f((u16)b[idx]);
    biasf[z * 256 + idx] = bv;
  }
}

// ---------------- QKV projection: 256x64 tile, direct-x staging ----------------
// grid (64, 4, 3), 256 thr. A staged from x (fp32 or bf16) with inline convert
// (VGPR -> ds_write_b128); B staged via global_load_lds from WTp.
template <typename T>
__global__ __launch_bounds__(256, 2) void qkv_gemm(const T* __restrict__ x, const u16* __restrict__ WTp,
                                                   const float* __restrict__ biasf,
                                                   u16* __restrict__ Qw, u16* __restrict__ Kw,
                                                   u16* __restrict__ VTg) {
  __shared__ __align__(16) u16 Al[256 * 128];   // 64 KB
  __shared__ __align__(16) u16 Bl[64 * 128];    // 16 KB
  const int tid = threadIdx.x, w = tid >> 6, lane = tid & 63;
  const int l16 = lane & 15, quad = lane >> 4;
  const int z = blockIdx.z, n0 = blockIdx.y * 64, m0 = blockIdx.x * 256;
  const u16* Bb = WTp + z * WZSTR + (size_t)n0 * 128;
  f32x4 acc[4][4];
#pragma unroll
  for (int mm = 0; mm < 4; ++mm)
#pragma unroll
    for (int nb = 0; nb < 4; ++nb) acc[mm][nb] = (f32x4){0.f, 0.f, 0.f, 0.f};

#pragma unroll
  for (int p = 0; p < 2; ++p) {
    __syncthreads();
    const u16* Bp = Bb + p * WPSTR;
#pragma unroll
    for (int i = 0; i < 16; ++i) {                // A: 256 rows x 16 chunks = 4096
      int slot = i * 256 + tid;
      int row = slot >> 4, pc = slot & 15, c = pc ^ (row & 15);
      const T* src = x + (size_t)(m0 + row) * 256 + p * 128 + c * 8;
      u32x4 dd;
      if constexpr (sizeof(T) == 4) {
        f32x4 v0 = *(const f32x4*)src;
        f32x4 v1 = *(const f32x4*)(src + 4);
        dd = (u32x4){ pack_rne(v0[0], v0[1]), pack_rne(v0[2], v0[3]),
                      pack_rne(v1[0], v1[1]), pack_rne(v1[2], v1[3]) };
      } else {
        dd = *(const u32x4*)src;
      }
      *(u32x4*)&Al[slot * 8] = dd;
    }
#pragma unroll
    for (int i = 0; i < 4; ++i) {                 // B: 64 rows x 16 chunks = 1024
      int slot = i * 256 + tid;
      int row = slot >> 4, pc = slot & 15, c = pc ^ (row & 15);
      cp16(Bp + (size_t)row * 128 + c * 8, Bl + slot * 8);
    }
    __syncthreads();
#pragma unroll
    for (int kc = 0; kc < 4; ++kc) {
      int ch = ((kc * 4 + quad) ^ l16) * 8;
      bf16x8 a[4], b[4];
#pragma unroll
      for (int mm = 0; mm < 4; ++mm)
        a[mm] = *(const bf16x8*)&Al[(w * 64 + mm * 16 + l16) * 128 + ch];
#pragma unroll
      for (int nb = 0; nb < 4; ++nb)
        b[nb] = *(const bf16x8*)&Bl[(nb * 16 + l16) * 128 + ch];
#pragma unroll
      for (int mm = 0; mm < 4; ++mm)
#pragma unroll
        for (int nb = 0; nb < 4; ++nb)
          acc[mm][nb] = mfma16(a[mm], b[nb], acc[mm][nb]);
    }
  }

  const float* bp = biasf + z * 256;
  const int bb = m0 >> 11, s0 = m0 & 2047, h = blockIdx.y;
  if (z < 2) {
    u16* dst = (z == 0) ? Qw : Kw;
    const float sc = (z == 0) ? ATTN_SC : 1.0f;
#pragma unroll
    for (int mm = 0; mm < 4; ++mm)
#pragma unroll
      for (int nb = 0; nb < 4; ++nb) {
        int d = nb * 16 + l16;
        float bv = bp[n0 + d];
#pragma unroll
        for (int r = 0; r < 4; ++r) {
          int s = s0 + w * 64 + mm * 16 + quad * 4 + r;
          dst[(((size_t)(bb * 4 + h) * 2048) + s) * 64 + d] = f2b((acc[mm][nb][r] + bv) * sc);
        }
      }
  } else {
    // V: transpose 256(s) x 64(d) tile through Al, store V^T [B,H,hd,S] coalesced
    __syncthreads();
#pragma unroll
    for (int mm = 0; mm < 4; ++mm)
#pragma unroll
      for (int nb = 0; nb < 4; ++nb) {
        int d = nb * 16 + l16;
        float bv = bp[n0 + d];
        f32x4 v = acc[mm][nb];
        u32x2 dd = { pack_rne(v[0] + bv, v[1] + bv), pack_rne(v[2] + bv, v[3] + bv) };
        int cch = w * 8 + mm * 2 + (quad >> 1);
        *(u32x2*)&Al[d * 256 + ((cch ^ (d & 31))) * 8 + (quad & 1) * 4] = dd;
      }
    __syncthreads();
#pragma unroll
    for (int i = 0; i < 8; ++i) {
      int slot = i * 256 + tid;                            // 64 d-rows x 32 chunks
      int d = slot >> 5, pc = slot & 31;
      u32x4 vv = *(const u32x4*)&Al[d * 256 + ((pc ^ (d & 31))) * 8];
      *(u32x4*)(VTg + (((size_t)(bb * 4 + h) * 64) + d) * 2048 + s0 + pc * 8) = vv;
    }
  }
}

// ---------------- fused flash attention: 32 q/wave, K-split x2, 40KB LDS ----------------
// grid (16 qtiles, 32 bh, 2 khalf), block 256 (4 waves) -> 1024 blocks = exactly
// 4/CU resident (zero tail). Per-wave 2KB P buffer SHARED between q-groups:
// g-phases serialized (same LDS addresses; wave-in-order DS keeps it correct).
__global__ __launch_bounds__(256, 4) void attn(const u16* __restrict__ Q, const u16* __restrict__ K,
                                               const u16* __restrict__ VT,
                                               u16* __restrict__ P0, u16* __restrict__ P1,
                                               float* __restrict__ dnb) {
  __shared__ __align__(16) u16 Kt[2][64 * 64];     // 16 KB  [key][d], swizzled ^(row&7)
  __shared__ __align__(16) u16 VTt[2][64 * 64];    // 16 KB  [d][key]
  __shared__ __align__(16) u16 Pt[4][16 * 64];     //  8 KB  per-wave, shared across g
  const int tid = threadIdx.x;
  const int w = tid >> 6, lane = tid & 63;
  const int l16 = lane & 15, quad = lane >> 4;
  const int bh = blockIdx.y, q0 = blockIdx.x * 128, z = blockIdx.z;
  const u16* Qp = Q + (size_t)bh * 2048 * 64;
  const u16* Kp = K + (size_t)bh * 2048 * 64 + (size_t)z * 1024 * 64;
  const u16* Vp = VT + (size_t)bh * 64 * 2048 + z * 1024;   // [d][s], s-offset
  u16* Ptw = Pt[w];

  bf16x8 qf[2][2];                                 // [qgroup][kc]
#pragma unroll
  for (int g = 0; g < 2; ++g) {
    int qrow = q0 + w * 32 + g * 16 + l16;
    qf[g][0] = *(const bf16x8*)(Qp + (size_t)qrow * 64 + quad * 8);
    qf[g][1] = *(const bf16x8*)(Qp + (size_t)qrow * 64 + 32 + quad * 8);
  }

  f32x4 acc[2][4];                                 // [qgroup][d-block]
#pragma unroll
  for (int g = 0; g < 2; ++g)
#pragma unroll
    for (int nb = 0; nb < 4; ++nb) acc[g][nb] = (f32x4){0.f, 0.f, 0.f, 0.f};
  float dn[2] = {0.f, 0.f};

  // staging: 512 chunks/tensor over 256 threads -> 2 each; swizzle ^(row&7)
  const int sl0 = tid, sl1 = 256 + tid;
  const int r0 = sl0 >> 3, c0 = (sl0 & 7) ^ (r0 & 7);
  const int r1 = sl1 >> 3, c1 = (sl1 & 7) ^ (r1 & 7);

#define STAGE(kt_, buf_)                                                                   \
  do {                                                                                     \
    cp16(Kp + (size_t)((kt_) * 64 + r0) * 64 + c0 * 8, &Kt[buf_][(w * 64) * 8]);           \
    cp16(Kp + (size_t)((kt_) * 64 + r1) * 64 + c1 * 8, &Kt[buf_][(256 + w * 64) * 8]);     \
    cp16(Vp + (size_t)r0 * 2048 + (kt_) * 64 + c0 * 8, &VTt[buf_][(w * 64) * 8]);          \
    cp16(Vp + (size_t)r1 * 2048 + (kt_) * 64 + c1 * 8, &VTt[buf_][(256 + w * 64) * 8]);    \
  } while (0)

  STAGE(0, 0);

  for (int kt = 0; kt < 16; ++kt) {
    const int buf = kt & 1;
    __builtin_amdgcn_s_waitcnt(0x0F70 /* vmcnt(0) */);    // my prefetch landed
    __asm__ __volatile__("" ::: "memory");
    __builtin_amdgcn_s_barrier();                          // raw: no compiler drain
    __asm__ __volatile__("" ::: "memory");
    if (kt < 15) STAGE(kt + 1, buf ^ 1);

    const u16* KtB = Kt[buf];
    const u16* VtB = VTt[buf];

    // S^T = K * Q^T : st[g][nbK] reg r -> key = nbK*16+quad*4+r, q = g*16+l16
    f32x4 st[2][4];
#pragma unroll
    for (int g = 0; g < 2; ++g)
#pragma unroll
      for (int nb = 0; nb < 4; ++nb) st[g][nb] = (f32x4){0.f, 0.f, 0.f, 0.f};
#pragma unroll
    for (int kc = 0; kc < 2; ++kc) {
#pragma unroll
      for (int nbK = 0; nbK < 4; ++nbK) {
        bf16x8 a = *(const bf16x8*)&KtB[(nbK * 16 + l16) * 64 + (((kc * 4 + quad) ^ (l16 & 7))) * 8];
        st[0][nbK] = mfma16(a, qf[0][kc], st[0][nbK]);     // A-frag reused for both groups
        st[1][nbK] = mfma16(a, qf[1][kc], st[1][nbK]);
      }
    }

    // V-frags (shared across both q-groups); loaded after QK so K-frag regs recycle
    bf16x8 vbr[2][4];
#pragma unroll
    for (int m = 0; m < 2; ++m)
#pragma unroll
      for (int nbD = 0; nbD < 4; ++nbD)
        vbr[m][nbD] = *(const bf16x8*)&VtB[(nbD * 16 + l16) * 64 + (((m * 4 + quad) ^ (l16 & 7))) * 8];

    // per-group: P = exp2(st) (exact, no max), write P, PV MFMAs. Shared Ptw:
    // g1's writes can't pass g0's reads (wave-in-order DS, identical addresses).
#pragma unroll
    for (int g = 0; g < 2; ++g) {
#pragma unroll
      for (int nbK = 0; nbK < 4; ++nbK) {
        float p0 = exp2f(st[g][nbK][0]), p1 = exp2f(st[g][nbK][1]);
        float p2 = exp2f(st[g][nbK][2]), p3 = exp2f(st[g][nbK][3]);
        dn[g] += (p0 + p1) + (p2 + p3);
        u32x2 dd = { pack_trunc(p0, p1), pack_trunc(p2, p3) };
        int cch = nbK * 2 + (quad >> 1);
        *(u32x2*)&Ptw[l16 * 64 + ((cch ^ (l16 & 7))) * 8 + (quad & 1) * 4] = dd;
      }
#pragma unroll
      for (int m = 0; m < 2; ++m) {
        bf16x8 pb = *(const bf16x8*)&Ptw[l16 * 64 + (((m * 4 + quad) ^ (l16 & 7))) * 8];
#pragma unroll
        for (int nbD = 0; nbD < 4; ++nbD)
          acc[g][nbD] = mfma16(vbr[m][nbD], pb, acc[g][nbD]);
      }
    }
  }
#undef STAGE

  // denom reduce across quads sharing q=l16; store per-q denom
  u16* pdst = z ? P1 : P0;
#pragma unroll
  for (int g = 0; g < 2; ++g) {
    float d = dn[g];
    d += __shfl_xor(d, 16);
    d += __shfl_xor(d, 32);
    if (quad == 0)
      dnb[z * 65536 + bh * 2048 + q0 + w * 32 + g * 16 + l16] = d;
  }

  // epilogue: UNNORMALIZED partials, per-g transpose through shared Ptw
#pragma unroll
  for (int g = 0; g < 2; ++g) {
#pragma unroll
    for (int nbD = 0; nbD < 4; ++nbD) {
      f32x4 v = acc[g][nbD];
      u32x2 dd = { pack_rne(v[0], v[1]), pack_rne(v[2], v[3]) };
      int cch = nbD * 2 + (quad >> 1);
      *(u32x2*)&Ptw[l16 * 64 + ((cch ^ (l16 & 7))) * 8 + (quad & 1) * 4] = dd;
    }
#pragma unroll
    for (int cc = 0; cc < 2; ++cc) {
      int slot = cc * 64 + lane;                   // 16 q-rows x 8 chunks
      int row = slot >> 3, pc = slot & 7;
      u32x4 vv = *(const u32x4*)&Ptw[row * 64 + ((pc ^ (row & 7))) * 8];
      size_t qg = q0 + w * 32 + g * 16 + row;
      *(u32x4*)(pdst + (((size_t)bh * 2048) + qg) * 64 + pc * 8) = vv;
    }
  }
}

// ---------------- combine (fallback path only) ----------------
__global__ __launch_bounds__(256) void combine(const u16* __restrict__ p0, const u16* __restrict__ p1,
                                               const float* __restrict__ dnb, u16* __restrict__ ctxc) {
  int t = blockIdx.x * 256 + threadIdx.x;          // 524288 = 32bh * 2048q * 8chunks
  int chunk = t & 7, q = (t >> 3) & 2047, bh = t >> 14;
  size_t idx = ((((size_t)bh * 2048) + q) * 64) + chunk * 8;
  u32x4 a = *(const u32x4*)(p0 + idx);
  u32x4 b = *(const u32x4*)(p1 + idx);
  float l = 1.0f / (dnb[bh * 2048 + q] + dnb[65536 + bh * 2048 + q]);
  u32x4 o;
#pragma unroll
  for (int i = 0; i < 4; ++i) {
    float lo = (b2f_lo(a[i]) + b2f_lo(b[i])) * l;
    float hi = (b2f_hi(a[i]) + b2f_hi(b[i])) * l;
    o[i] = pack_rne(lo, hi);
  }
  *(u32x4*)(ctxc + idx) = o;                        // same head-major layout
}

// ---------------- output projection (fused merge+normalize in A-staging) ----------------
// A[m][col]: col's head h = col>>6; staged value = (p0+p1)*linv(bh,q), so the
// per-head normalization folds into the GEMM's A operand. MERGED=false reads a
// single pre-combined ctx (fallback).
template <bool OUT_BF16, bool MERGED>
__global__ __launch_bounds__(256) void out_gemm(const u16* __restrict__ p0, const u16* __restrict__ p1,
                                                const float* __restrict__ dnb,
                                                const u16* __restrict__ WTp,
                                                const float* __restrict__ bo, void* __restrict__ outv) {
  __shared__ __align__(16) u16 Al[128 * 128];
  __shared__ __align__(16) u16 Bl[64 * 128];
  const int tid = threadIdx.x, w = tid >> 6, lane = tid & 63;
  const int l16 = lane & 15, quad = lane >> 4;
  const int n0 = blockIdx.y * 64, m0 = blockIdx.x * 128;
  const u16* Bb = WTp + 3 * WZSTR + (size_t)n0 * 128;
  f32x4 acc[2][4];
#pragma unroll
  for (int mm = 0; mm < 2; ++mm)
#pragma unroll
    for (int nb = 0; nb < 4; ++nb) acc[mm][nb] = (f32x4){0.f, 0.f, 0.f, 0.f};

#pragma unroll
  for (int p = 0; p < 2; ++p) {
    __syncthreads();
    const u16* Bp = Bb + p * WPSTR;
#pragma unroll
    for (int i = 0; i < 8; ++i) {                  // A: 128 rows x 16 chunks
      int slot = i * 256 + tid;
      int row = slot >> 4, pc = slot & 15, c = pc ^ (row & 15);
      int m = m0 + row, bb = m >> 11, q = m & 2047;
      int col0 = p * 128 + c * 8, h = col0 >> 6, d0 = col0 & 63;
      size_t idx = (((size_t)(bb * 4 + h) * 2048) + q) * 64 + d0;
      u32x4 dd;
      if constexpr (MERGED) {
        u32x4 a = *(const u32x4*)(p0 + idx);
        u32x4 b = *(const u32x4*)(p1 + idx);
        float l = 1.0f / (dnb[(bb * 4 + h) * 2048 + q] + dnb[65536 + (bb * 4 + h) * 2048 + q]);
#pragma unroll
        for (int j = 0; j < 4; ++j)
          dd[j] = pack_rne((b2f_lo(a[j]) + b2f_lo(b[j])) * l,
                           (b2f_hi(a[j]) + b2f_hi(b[j])) * l);
      } else {
        dd = *(const u32x4*)(p0 + idx);            // pre-combined ctx, head-major
      }
      *(u32x4*)&Al[slot * 8] = dd;
    }
#pragma unroll
    for (int i = 0; i < 4; ++i) {
      int slot = i * 256 + tid;
      int row = slot >> 4, pc = slot & 15, c = pc ^ (row & 15);
      cp16(Bp + (size_t)row * 128 + c * 8, Bl + slot * 8);
    }
    __syncthreads();
#pragma unroll
    for (int kc = 0; kc < 4; ++kc) {
      int ch = ((kc * 4 + quad) ^ l16) * 8;
      bf16x8 a0 = *(const bf16x8*)&Al[(w * 32 + l16) * 128 + ch];
      bf16x8 a1 = *(const bf16x8*)&Al[(w * 32 + 16 + l16) * 128 + ch];
#pragma unroll
      for (int nb = 0; nb < 4; ++nb) {
        bf16x8 b = *(const bf16x8*)&Bl[(nb * 16 + l16) * 128 + ch];
        acc[0][nb] = mfma16(a0, b, acc[0][nb]);
        acc[1][nb] = mfma16(a1, b, acc[1][nb]);
      }
    }
  }
#pragma unroll
  for (int mm = 0; mm < 2; ++mm)
#pragma unroll
    for (int nb = 0; nb < 4; ++nb) {
      int n = n0 + nb * 16 + l16;
      float bv = bo[n];
#pragma unroll
      for (int r = 0; r < 4; ++r) {
        size_t m = m0 + w * 32 + mm * 16 + quad * 4 + r;
        float v = acc[mm][nb][r] + bv;
        if constexpr (OUT_BF16) ((u16*)outv)[m * 256 + n] = f2b(v);
        else                    ((float*)outv)[m * 256 + n] = v;
      }
    }
}

// ---------------- host ----------------
extern "C" void kernel_launch(void* const* d_in, const int* in_sizes, int n_in,
                              void* d_out, int out_size, void* d_ws, size_t ws_size,
                              hipStream_t stream) {
  bool f32in = true;
  {
    void* basep = nullptr; size_t sz = 0;
    hipError_t e = hipMemGetAddressRange((hipDeviceptr_t*)&basep, &sz, (hipDeviceptr_t)d_in[0]);
    if (e == hipSuccess && sz > 0) f32in = sz >= (size_t)in_sizes[0] * 4;
    else f32in = false;
  }

  char* ws = (char*)d_ws;
  u16*   p0    = (u16*)(ws + 0);          // 8 MB: attn partial, half 0
  u16*   WTp   = (u16*)(ws + 8388608);    // 512 KB: W^T panel-major [4][2][256][128]
  float* biasf = (float*)(ws + 8912896);  // 4 KB
  u16*   Qw    = (u16*)(ws + 8916992);    // 8 MB [B,H,S,hd], pre-scaled by ATTN_SC
  u16*   Kw    = (u16*)(ws + 17305600);   // 8 MB [B,H,S,hd]
  u16*   VTg   = (u16*)(ws + 25694208);   // 8 MB [B,H,hd,S]
  float* dnb   = (float*)(ws + 34082816); // 512 KB: per-q denom, 2 k-halves
  const size_t P1_OFF = 34607104;         // 8 MB: attn partial half 1 (fused path)
  bool fused = ws_size >= P1_OFF + 8388608;
  u16* p1 = fused ? (u16*)(ws + P1_OFF) : (u16*)d_out;   // fallback: d_out scratch (combine only READS it)
  u16* ctxc = Qw;                          // fallback combined ctx (Q dead after attn)

  if (f32in) {
    prep<float><<<1024, 256, 0, stream>>>(
        (const float*)d_in[1], (const float*)d_in[3], (const float*)d_in[5], (const float*)d_in[7],
        (const float*)d_in[2], (const float*)d_in[4], (const float*)d_in[6], (const float*)d_in[8],
        WTp, biasf);
    qkv_gemm<float><<<dim3(64, 4, 3), 256, 0, stream>>>((const float*)d_in[0], WTp, biasf, Qw, Kw, VTg);
  } else {
    prep<u16><<<1024, 256, 0, stream>>>(
        (const u16*)d_in[1], (const u16*)d_in[3], (const u16*)d_in[5], (const u16*)d_in[7],
        (const u16*)d_in[2], (const u16*)d_in[4], (const u16*)d_in[6], (const u16*)d_in[8],
        WTp, biasf);
    qkv_gemm<u16><<<dim3(64, 4, 3), 256, 0, stream>>>((const u16*)d_in[0], WTp, biasf, Qw, Kw, VTg);
  }
  attn<<<dim3(16, 32, 2), 256, 0, stream>>>(Qw, Kw, VTg, p0, p1, dnb);
  if (fused) {
    if (f32in) out_gemm<false, true><<<dim3(128, 4), 256, 0, stream>>>(p0, p1, dnb, WTp, biasf + 3 * 256, d_out);
    else       out_gemm<true,  true><<<dim3(128, 4), 256, 0, stream>>>(p0, p1, dnb, WTp, biasf + 3 * 256, d_out);
  } else {
    combine<<<2048, 256, 0, stream>>>(p0, p1, dnb, ctxc);
    if (f32in) out_gemm<false, false><<<dim3(128, 4), 256, 0, stream>>>(ctxc, nullptr, dnb, WTp, biasf + 3 * 256, d_out);
    else       out_gemm<true,  false><<<dim3(128, 4), 256, 0, stream>>>(ctxc, nullptr, dnb, WTp, biasf + 3 * 256, d_out);
  }
}